// Round 4
// baseline (17.064 us; speedup 1.0000x reference)
//
#include <hip/hip_runtime.h>

// Quanv2d — closed-form evaluation, 4 patches per thread (rows r, r+16, r+32,
// r+48) to cut wave count 4x (8192 -> 2048 waves, 2048 -> 512 WGs).
//
//   z_q = cos(th_q)*C_q + S_q*( sin^2(th_q)cos(th_{q-1})*C_{q+1}
//                             + sin(th_q)cos(th_q)sin(th_{q-1})*C_{q-1} )
// with C_q = cos(pi f_q), S_q = sin(pi f_q), th_q = W[3+q], indices mod 4.
//
// Grid: blockIdx.y = image b (128), blockIdx.x = row-base group (4).
// threadIdx.x bits [7:6] -> row-base sub, bits [5:0] -> patch column cc.
// Thread's rows: rb + {0,16,32,48}, rb in [0,16). Row 63 + col 63 masked.

__global__ __launch_bounds__(256)
void quanv_kernel(const float* __restrict__ X, const float* __restrict__ W,
                  float* __restrict__ out) {
    int b  = blockIdx.y;
    int rb = (blockIdx.x << 2) | (threadIdx.x >> 6);   // [0,16)
    int cc = threadIdx.x & 63;
    if (cc >= 63) return;

    // Uniform weight trig (angles in [0,2pi) -> revolutions in [0,1)).
    const float INV2PI = 0.15915494309189535f;
    float sn[4], cs[4];
#pragma unroll
    for (int q = 0; q < 4; ++q) {
        float rev = W[3 + q] * INV2PI;
        sn[q] = __builtin_amdgcn_sinf(rev);
        cs[q] = __builtin_amdgcn_cosf(rev);
    }
    // Precombine weight-only coefficients: z_q = A_q*C_q + S_q*(E_q*C_{q+1} + F_q*C_{q-1})
    float Eq[4], Fq[4];
#pragma unroll
    for (int q = 0; q < 4; ++q) {
        int qm = (q + 3) & 3;
        Eq[q] = sn[q] * sn[q] * cs[qm];
        Fq[q] = sn[q] * cs[q] * sn[qm];
    }

    const float* ximg = X + (size_t)b * 49152 + 2 * cc;
    float4* obase = reinterpret_cast<float4*>(out) + b * 3969 + cc;

#pragma unroll
    for (int k = 0; k < 4; ++k) {
        int r = rb + 16 * k;
        if (r >= 63) break;   // only rb==15, k==3 masked
        const float* xp = ximg + r * 256;
        float f0 = xp[0], f1 = xp[1], f2 = xp[2], f3 = xp[3];

        float C[4], S[4];
        C[0] = __builtin_amdgcn_cosf(0.5f * f0);
        S[0] = __builtin_amdgcn_sinf(0.5f * f0);
        C[1] = __builtin_amdgcn_cosf(0.5f * f1);
        S[1] = __builtin_amdgcn_sinf(0.5f * f1);
        C[2] = __builtin_amdgcn_cosf(0.5f * f2);
        S[2] = __builtin_amdgcn_sinf(0.5f * f2);
        C[3] = __builtin_amdgcn_cosf(0.5f * f3);
        S[3] = __builtin_amdgcn_sinf(0.5f * f3);

        float z[4];
#pragma unroll
        for (int q = 0; q < 4; ++q) {
            int qm = (q + 3) & 3, qp = (q + 1) & 3;
            z[q] = cs[q] * C[q] + S[q] * (Eq[q] * C[qp] + Fq[q] * C[qm]);
        }
        obase[r * 63] = make_float4(z[0], z[1], z[2], z[3]);
    }
}

extern "C" void kernel_launch(void* const* d_in, const int* in_sizes, int n_in,
                              void* d_out, int out_size, void* d_ws, size_t ws_size,
                              hipStream_t stream) {
    const float* X = (const float*)d_in[0];
    const float* W = (const float*)d_in[1];
    float* out = (float*)d_out;
    dim3 grid(4, 128);   // 512 WGs, 2048 waves
    quanv_kernel<<<grid, 256, 0, stream>>>(X, W, out);
}

// Round 6
// 10.888 us; speedup vs baseline: 1.5672x; 1.5672x over previous
//
#include <hip/hip_runtime.h>

// Quanv2d — closed-form evaluation; one patch/thread (R3 geometry), with
// lane-shared loads: lane cc loads one aligned float2 (disjoint; the wave
// reads one contiguous 512 B row segment), neighbor pair via shfl_down.
// Nontemporal store (native vector type) for the streaming output.
//
//   z_q = cos(th_q)*C_q + S_q*( sin^2(th_q)cos(th_{q-1})*C_{q+1}
//                             + sin(th_q)cos(th_q)sin(th_{q-1})*C_{q-1} )
// C_q = cos(pi f_q), S_q = sin(pi f_q), th_q = W[3+q], indices mod 4.

typedef float f32x4 __attribute__((ext_vector_type(4)));

__global__ __launch_bounds__(256)
void quanv_kernel(const float* __restrict__ X, const float* __restrict__ W,
                  float* __restrict__ out) {
    int b  = blockIdx.y;
    int r  = (blockIdx.x << 2) | (threadIdx.x >> 6);
    int cc = threadIdx.x & 63;
    if (r >= 63) return;   // wave-uniform exit (only blockIdx.x==15, top wave)

    // Lane cc owns floats [2cc, 2cc+1] of row 2r: one aligned float2.
    const float* xp = X + (size_t)b * 49152 + r * 256 + 2 * cc;
    float2 v = *reinterpret_cast<const float2*>(xp);
    float f0 = v.x, f1 = v.y;
    // Patch needs floats 2cc..2cc+3: neighbor lane's pair in-register.
    float f2 = __shfl_down(f0, 1, 64);
    float f3 = __shfl_down(f1, 1, 64);

    // C_j = cos(pi f_j); hardware trig takes revolutions (2*pi rad = 1.0).
    float C[4], S[4];
    C[0] = __builtin_amdgcn_cosf(0.5f * f0);
    S[0] = __builtin_amdgcn_sinf(0.5f * f0);
    C[1] = __builtin_amdgcn_cosf(0.5f * f1);
    S[1] = __builtin_amdgcn_sinf(0.5f * f1);
    C[2] = __builtin_amdgcn_cosf(0.5f * f2);
    S[2] = __builtin_amdgcn_sinf(0.5f * f2);
    C[3] = __builtin_amdgcn_cosf(0.5f * f3);
    S[3] = __builtin_amdgcn_sinf(0.5f * f3);

    // Uniform weight trig (angles in [0,2pi) -> revolutions in [0,1)).
    const float INV2PI = 0.15915494309189535f;
    float sn[4], cs[4];
#pragma unroll
    for (int q = 0; q < 4; ++q) {
        float rev = W[3 + q] * INV2PI;
        sn[q] = __builtin_amdgcn_sinf(rev);
        cs[q] = __builtin_amdgcn_cosf(rev);
    }

    float z[4];
#pragma unroll
    for (int q = 0; q < 4; ++q) {
        int qm = (q + 3) & 3, qp = (q + 1) & 3;
        float E = sn[q] * sn[q] * cs[qm];   // sin^2(th_q) cos(th_{q-1})
        float F = sn[q] * cs[q] * sn[qm];   // sin(th_q) cos(th_q) sin(th_{q-1})
        z[q] = cs[q] * C[q] + S[q] * (E * C[qp] + F * C[qm]);
    }

    if (cc < 63) {
        int oi = b * 3969 + r * 63 + cc;
        f32x4 zv = {z[0], z[1], z[2], z[3]};
        __builtin_nontemporal_store(zv, reinterpret_cast<f32x4*>(out) + oi);
    }
}

extern "C" void kernel_launch(void* const* d_in, const int* in_sizes, int n_in,
                              void* d_out, int out_size, void* d_ws, size_t ws_size,
                              hipStream_t stream) {
    const float* X = (const float*)d_in[0];
    const float* W = (const float*)d_in[1];
    float* out = (float*)d_out;
    dim3 grid(16, 128);   // 2048 WGs, 8192 waves
    quanv_kernel<<<grid, 256, 0, stream>>>(X, W, out);
}

// Round 7
// 10.425 us; speedup vs baseline: 1.6369x; 1.0444x over previous
//
#include <hip/hip_runtime.h>

// Quanv2d — closed-form evaluation, division-free geometric grid mapping.
// (Best-measured variant: R3, 10.43 µs. R4 multi-patch and R6 lane-shared
// loads both regressed; kernel sits on the fixed dispatch floor, ~8 µs,
// with ~2 µs of actual memory work: 4.1 MB fetch + 8.1 MB write.)
//
//   z_q = cos(th_q)*C_q + S_q*( sin^2(th_q)cos(th_{q-1})*C_{q+1}
//                             + sin(th_q)cos(th_q)sin(th_{q-1})*C_{q-1} )
// with C_q = cos(pi f_q), S_q = sin(pi f_q), th_q = W[3+q], indices mod 4.
//
// Grid: blockIdx.y = image b (128), blockIdx.x = row-group (16 x 4 rows),
// threadIdx.x: bits [7:6] = row-in-group, bits [5:0] = patch column cc.
// Lane cc=63 and row 63 are masked (63x63 patches). No integer division.

__global__ __launch_bounds__(256)
void quanv_kernel(const float* __restrict__ X, const float* __restrict__ W,
                  float* __restrict__ out) {
    int b  = blockIdx.y;
    int r  = (blockIdx.x << 2) | (threadIdx.x >> 6);
    int cc = threadIdx.x & 63;
    if (r >= 63 || cc >= 63) return;

    // X[b, 0, 2r, 2cc + k]; image stride 3*128*128 floats
    const float* xp = X + (size_t)b * 49152 + r * 256 + 2 * cc;
    float f0 = xp[0], f1 = xp[1], f2 = xp[2], f3 = xp[3];

    // C_j = cos(pi f_j); hardware trig takes revolutions (2*pi rad = 1.0).
    float C[4], S[4];
    C[0] = __builtin_amdgcn_cosf(0.5f * f0);
    S[0] = __builtin_amdgcn_sinf(0.5f * f0);
    C[1] = __builtin_amdgcn_cosf(0.5f * f1);
    S[1] = __builtin_amdgcn_sinf(0.5f * f1);
    C[2] = __builtin_amdgcn_cosf(0.5f * f2);
    S[2] = __builtin_amdgcn_sinf(0.5f * f2);
    C[3] = __builtin_amdgcn_cosf(0.5f * f3);
    S[3] = __builtin_amdgcn_sinf(0.5f * f3);

    // Uniform weight trig (angles in [0,2pi) -> revolutions in [0,1)).
    const float INV2PI = 0.15915494309189535f;
    float sn[4], cs[4];
#pragma unroll
    for (int q = 0; q < 4; ++q) {
        float rev = W[3 + q] * INV2PI;
        sn[q] = __builtin_amdgcn_sinf(rev);
        cs[q] = __builtin_amdgcn_cosf(rev);
    }

    float z[4];
#pragma unroll
    for (int q = 0; q < 4; ++q) {
        int qm = (q + 3) & 3, qp = (q + 1) & 3;
        float E = sn[q] * sn[q] * cs[qm];   // sin^2(th_q) cos(th_{q-1})
        float F = sn[q] * cs[q] * sn[qm];   // sin(th_q) cos(th_q) sin(th_{q-1})
        z[q] = cs[q] * C[q] + S[q] * (E * C[qp] + F * C[qm]);
    }

    // out float4 index: b*3969 + r*63 + cc (contiguous per wave-row)
    int oi = b * 3969 + r * 63 + cc;
    reinterpret_cast<float4*>(out)[oi] = make_float4(z[0], z[1], z[2], z[3]);
}

extern "C" void kernel_launch(void* const* d_in, const int* in_sizes, int n_in,
                              void* d_out, int out_size, void* d_ws, size_t ws_size,
                              hipStream_t stream) {
    const float* X = (const float*)d_in[0];
    const float* W = (const float*)d_in[1];
    float* out = (float*)d_out;
    dim3 grid(16, 128);   // 16 row-groups x 128 images
    quanv_kernel<<<grid, 256, 0, stream>>>(X, W, out);
}